// Round 1
// baseline (354.294 us; speedup 1.0000x reference)
//
#include <hip/hip_runtime.h>
#include <math.h>

// Problem constants
#define C_IN   256
#define HW_    4096      // 64*64
#define B_     8
#define NTOT   32768     // B_*HW_
#define KW_    769       // 3*C+1
#define NPIX_BN 32768.0f // B*H*W for batchnorm

// ---------------------------------------------------------------------------
// Kernel 1: attn[n] = sigmoid( sum_c f_s[b,c,p] * sfb[b,c,p] )
// Block: 256 threads handles 64 pixels; 4 channel-groups of 64 channels each.
// ---------------------------------------------------------------------------
__global__ __launch_bounds__(256) void attn_kernel(
    const float* __restrict__ f_s, const float* __restrict__ sfb,
    float* __restrict__ attn)
{
    __shared__ float sm[256];
    int t = threadIdx.x;
    int tc = t >> 6;          // channel group 0..3
    int tp = t & 63;          // pixel within tile
    int pb = blockIdx.x * 64; // global pixel base (0..32704), never crosses b
    int b  = pb >> 12;
    int p  = (pb & 4095) + tp;
    const float* fp = f_s + (size_t)b * C_IN * HW_ + p;
    const float* sp = sfb + (size_t)b * C_IN * HW_ + p;
    float acc = 0.f;
    int c0 = tc * 64;
    #pragma unroll 8
    for (int c = c0; c < c0 + 64; ++c)
        acc += fp[(size_t)c * HW_] * sp[(size_t)c * HW_];
    sm[t] = acc;
    __syncthreads();
    if (t < 64) {
        float a = sm[t] + sm[t + 64] + sm[t + 128] + sm[t + 192];
        attn[pb + t] = 1.f / (1.f + expf(-a));
    }
}

// ---------------------------------------------------------------------------
// Kernel 2: distance transform (raw distance + per-sample max via atomicMax)
// grid (8, 16): blockIdx.x = sample, blockIdx.y = 256-pixel tile.
// 1024 threads: 4 threads per pixel split the fg list.
// ---------------------------------------------------------------------------
__global__ __launch_bounds__(1024) void dist_kernel(
    const float* __restrict__ mask, float* __restrict__ dist_raw,
    unsigned* __restrict__ dmax)
{
    __shared__ float2 fg[4096];
    __shared__ int cnt;
    __shared__ float wmax[16];
    int b = blockIdx.x, tile = blockIdx.y;
    int t = threadIdx.x;
    if (t == 0) cnt = 0;
    __syncthreads();
    const float* mb = mask + (size_t)b * 65536;
    // build fg list: m_s[i][j] = mask[4i][4j] > 0.5
    #pragma unroll
    for (int r = 0; r < 4; ++r) {
        int p = r * 1024 + t;
        int i = p >> 6, j = p & 63;
        if (mb[i * 1024 + j * 4] > 0.5f) {
            int idx = atomicAdd(&cnt, 1);
            fg[idx] = make_float2((float)i, (float)j);
        }
    }
    __syncthreads();
    int nfg = cnt;
    int pix = tile * 256 + (t >> 2);
    int q = t & 3;
    float py = (float)(pix >> 6), px = (float)(pix & 63);
    float m = 3.4e38f;
    for (int it = q; it < nfg; it += 4) {
        float dy = py - fg[it].x;
        float dx = px - fg[it].y;
        m = fminf(m, dy * dy + dx * dx);
    }
    m = fminf(m, __shfl_xor(m, 1, 64));
    m = fminf(m, __shfl_xor(m, 2, 64));
    float d = (nfg == 0) ? 1.0f : sqrtf(m);
    if (q == 0) dist_raw[b * HW_ + pix] = d;
    // block-wide max
    float mm = d;
    #pragma unroll
    for (int off = 1; off < 64; off <<= 1)
        mm = fmaxf(mm, __shfl_xor(mm, off, 64));
    if ((t & 63) == 0) wmax[t >> 6] = mm;
    __syncthreads();
    if (t == 0) {
        float M = wmax[0];
        #pragma unroll
        for (int i = 1; i < 16; ++i) M = fmaxf(M, wmax[i]);
        atomicMax(dmax + b, __float_as_uint(M)); // d>=0 -> uint order == float order
    }
}

// ---------------------------------------------------------------------------
// Kernel 3: fused triple-GEMM + dist/attn epilogue + BN partial stats.
// y[o,n] = W1.f_s + W2.sfb + attn[n]*(W3.f_s) + w_d[o]*dist_norm[n]
// Tile: 64 o x 64 n per block, 256 threads (16x16), 4x4 microtile, K-step 16.
// y written to d_out (staging); per-channel sum/sumsq via atomics.
// ---------------------------------------------------------------------------
__global__ __launch_bounds__(256) void gemm_kernel(
    const float* __restrict__ f_s, const float* __restrict__ sfb,
    const float* __restrict__ w, const float* __restrict__ attn,
    const float* __restrict__ dist_raw, const unsigned* __restrict__ dmax,
    float* __restrict__ y, float* __restrict__ gsum, float* __restrict__ gsumsq)
{
    __shared__ __align__(16) float Ws[3][16][68]; // [mat][k][o], pad 68 for aligned b128
    __shared__ __align__(16) float Bf[16][64];    // f_s tile [k][n]
    __shared__ __align__(16) float Bs[16][64];    // sfb tile [k][n]

    int bx = blockIdx.x;
    int ot = bx & 3, nt = bx >> 2;
    int oBase = ot * 64;
    int nBase = nt * 64;          // 64-pixel tile never crosses a sample
    int b = nBase >> 12;
    int pBase = nBase & 4095;
    int t = threadIdx.x;
    int to = t >> 4, tn = t & 15;

    float acc1[4][4] = {{0}}, acc2[4][4] = {{0}}, acc3[4][4] = {{0}};

    const float* fB = f_s + (size_t)b * C_IN * HW_ + pBase;
    const float* sB = sfb + (size_t)b * C_IN * HW_ + pBase;

    for (int k0 = 0; k0 < 256; k0 += 16) {
        // stage weights: 3 x (64 o x 16 k)
        {
            int kk = t & 15, ob = t >> 4;
            #pragma unroll
            for (int m = 0; m < 3; ++m) {
                #pragma unroll
                for (int r = 0; r < 4; ++r) {
                    int o = oBase + r * 16 + ob;
                    Ws[m][kk][r * 16 + ob] = w[(size_t)o * KW_ + m * 256 + k0 + kk];
                }
            }
        }
        // stage B tiles: 16 k x 64 n each
        {
            int pp = t & 63, kb = t >> 6;
            #pragma unroll
            for (int r = 0; r < 4; ++r) {
                int k = r * 4 + kb;
                Bf[k][pp] = fB[(size_t)(k0 + k) * HW_ + pp];
                Bs[k][pp] = sB[(size_t)(k0 + k) * HW_ + pp];
            }
        }
        __syncthreads();
        #pragma unroll
        for (int kk = 0; kk < 16; ++kk) {
            float4 w1 = *(const float4*)&Ws[0][kk][to * 4];
            float4 w2 = *(const float4*)&Ws[1][kk][to * 4];
            float4 w3 = *(const float4*)&Ws[2][kk][to * 4];
            float4 bf = *(const float4*)&Bf[kk][tn * 4];
            float4 bs = *(const float4*)&Bs[kk][tn * 4];
            const float w1a[4] = {w1.x, w1.y, w1.z, w1.w};
            const float w2a[4] = {w2.x, w2.y, w2.z, w2.w};
            const float w3a[4] = {w3.x, w3.y, w3.z, w3.w};
            const float bfa[4] = {bf.x, bf.y, bf.z, bf.w};
            const float bsa[4] = {bs.x, bs.y, bs.z, bs.w};
            #pragma unroll
            for (int i = 0; i < 4; ++i) {
                #pragma unroll
                for (int j = 0; j < 4; ++j) {
                    acc1[i][j] += w1a[i] * bfa[j];
                    acc2[i][j] += w2a[i] * bsa[j];
                    acc3[i][j] += w3a[i] * bfa[j];
                }
            }
        }
        __syncthreads();
    }

    // epilogue
    float dinv = 1.0f / (__uint_as_float(dmax[b]) + 1e-6f);
    int n0 = nBase + tn * 4;
    float at[4], dn[4];
    #pragma unroll
    for (int j = 0; j < 4; ++j) {
        at[j] = attn[n0 + j];
        dn[j] = dist_raw[n0 + j] * dinv;
    }
    float s[4], ss[4];
    #pragma unroll
    for (int i = 0; i < 4; ++i) {
        int o = oBase + to * 4 + i;
        float wd = w[(size_t)o * KW_ + 768];
        float4 yv;
        float sl = 0.f, ssl = 0.f;
        float vj[4];
        #pragma unroll
        for (int j = 0; j < 4; ++j) {
            float v = acc1[i][j] + acc2[i][j] + at[j] * acc3[i][j] + wd * dn[j];
            vj[j] = v;
            sl += v;
            ssl += v * v;
        }
        yv.x = vj[0]; yv.y = vj[1]; yv.z = vj[2]; yv.w = vj[3];
        float* yp = y + (size_t)(b * C_IN + o) * HW_ + (pBase + tn * 4);
        *(float4*)yp = yv;
        s[i] = sl; ss[i] = ssl;
    }
    // reduce over the 16 tn lanes (contiguous within a wave for fixed to)
    #pragma unroll
    for (int m = 8; m; m >>= 1) {
        #pragma unroll
        for (int i = 0; i < 4; ++i) {
            s[i]  += __shfl_xor(s[i],  m, 64);
            ss[i] += __shfl_xor(ss[i], m, 64);
        }
    }
    if (tn == 0) {
        #pragma unroll
        for (int i = 0; i < 4; ++i) {
            int o = oBase + to * 4 + i;
            atomicAdd(&gsum[o],   s[i]);
            atomicAdd(&gsumsq[o], ss[i]);
        }
    }
}

// ---------------------------------------------------------------------------
// Kernel 4: BN finalize + relu, in-place on y (= d_out).
// grid 2048 = (b,o) rows; 256 threads x 4 float4.
// ---------------------------------------------------------------------------
__global__ __launch_bounds__(256) void bn_kernel(
    const float* __restrict__ gsum, const float* __restrict__ gsumsq,
    const float* __restrict__ gamma, const float* __restrict__ beta,
    float* __restrict__ y)
{
    int bo = blockIdx.x;
    int o = bo & 255;
    float mean = gsum[o] * (1.0f / NPIX_BN);
    float var  = gsumsq[o] * (1.0f / NPIX_BN) - mean * mean;
    float sc = gamma[o] * rsqrtf(var + 1e-5f);
    float sh = beta[o] - mean * sc;
    float4* p = (float4*)(y + (size_t)bo * HW_);
    int t = threadIdx.x;
    #pragma unroll
    for (int r = 0; r < 4; ++r) {
        float4 v = p[r * 256 + t];
        v.x = fmaxf(v.x * sc + sh, 0.f);
        v.y = fmaxf(v.y * sc + sh, 0.f);
        v.z = fmaxf(v.z * sc + sh, 0.f);
        v.w = fmaxf(v.w * sc + sh, 0.f);
        p[r * 256 + t] = v;
    }
}

// ---------------------------------------------------------------------------
// ws layout (floats):
//   [0,      32768)  attn
//   [32768,  65536)  dist_raw
//   [65536,  65544)  dmax (uint bits)
//   [65552,  65808)  gsum[256]
//   [65808,  66064)  gsumsq[256]
// ---------------------------------------------------------------------------
extern "C" void kernel_launch(void* const* d_in, const int* in_sizes, int n_in,
                              void* d_out, int out_size, void* d_ws, size_t ws_size,
                              hipStream_t stream)
{
    const float* f_s   = (const float*)d_in[0];
    const float* sfb   = (const float*)d_in[1];
    const float* mask  = (const float*)d_in[2];
    const float* w     = (const float*)d_in[3];
    const float* gamma = (const float*)d_in[4];
    const float* beta  = (const float*)d_in[5];
    float* out = (float*)d_out;
    float* ws  = (float*)d_ws;

    float*    attn_b   = ws;
    float*    dist_raw = ws + 32768;
    unsigned* dmax     = (unsigned*)(ws + 65536);
    float*    gsum     = ws + 65552;
    float*    gsumsq   = ws + 65808;

    // zero dmax + gsum + gsumsq
    hipMemsetAsync(ws + 65536, 0, 2560, stream);

    attn_kernel<<<512, 256, 0, stream>>>(f_s, sfb, attn_b);
    dist_kernel<<<dim3(8, 16), 1024, 0, stream>>>(mask, dist_raw, dmax);
    gemm_kernel<<<2048, 256, 0, stream>>>(f_s, sfb, w, attn_b, dist_raw, dmax,
                                          out, gsum, gsumsq);
    bn_kernel<<<2048, 256, 0, stream>>>(gsum, gsumsq, gamma, beta, out);
}

// Round 2
// 247.027 us; speedup vs baseline: 1.4342x; 1.4342x over previous
//
#include <hip/hip_runtime.h>
#include <math.h>

#define C_IN   256
#define HW_    4096
#define KW_    769
#define NPIX_BN 32768.0f

typedef short bf16x8 __attribute__((ext_vector_type(8)));
typedef float f32x4  __attribute__((ext_vector_type(4)));
typedef unsigned short u16x4 __attribute__((ext_vector_type(4)));

__device__ inline unsigned short f2bf(float x){
    unsigned u = __float_as_uint(x);
    u += 0x7fffu + ((u >> 16) & 1u);      // RNE
    return (unsigned short)(u >> 16);
}

// ---------------------------------------------------------------------------
// prep_w: w fp32 [256][769] -> wprep bf16 fragment-ordered
// layout: chunk = ((m*8+ks)*4+kg)*256 + o, 8 k-contiguous bf16 per chunk
// ---------------------------------------------------------------------------
__global__ __launch_bounds__(256) void prep_w(
    const float* __restrict__ w, unsigned short* __restrict__ wp)
{
    int idx = blockIdx.x * 256 + threadIdx.x;     // 196608 total
    int j  = idx & 7;
    int o  = (idx >> 3) & 255;
    int t2 = idx >> 11;                           // m*32 + ks*4 + kg
    int kg = t2 & 3, ks = (t2 >> 2) & 7, m = t2 >> 5;
    int c  = m * 256 + ks * 32 + kg * 8 + j;
    wp[idx] = f2bf(w[(size_t)o * KW_ + c]);
}

// ---------------------------------------------------------------------------
// dist kernel: ballot-compacted fg list build + brute-force min distance
// ---------------------------------------------------------------------------
__global__ __launch_bounds__(1024) void dist_kernel(
    const float* __restrict__ mask, float* __restrict__ dist_raw,
    unsigned* __restrict__ dmax)
{
    __shared__ float2 fg[4096];
    __shared__ int cnt;
    __shared__ float wmax[16];
    int b = blockIdx.x, tile = blockIdx.y;
    int t = threadIdx.x, lane = t & 63;
    if (t == 0) cnt = 0;
    __syncthreads();
    const float* mb = mask + (size_t)b * 65536;
    #pragma unroll
    for (int r = 0; r < 4; ++r) {
        int pp = r * 1024 + t;
        int i = pp >> 6, j = pp & 63;
        bool pred = mb[i * 1024 + j * 4] > 0.5f;
        unsigned long long bal = __ballot(pred);
        int base = 0;
        if (lane == 0) base = atomicAdd(&cnt, __popcll(bal));
        base = __shfl(base, 0, 64);
        if (pred)
            fg[base + __popcll(bal & ((1ull << lane) - 1ull))] =
                make_float2((float)i, (float)j);
    }
    __syncthreads();
    int nfg = cnt;
    int pix = tile * 256 + (t >> 2);
    int q = t & 3;
    float py = (float)(pix >> 6), px = (float)(pix & 63);
    float m = 3.4e38f;
    for (int it = q; it < nfg; it += 4) {
        float dy = py - fg[it].x;
        float dx = px - fg[it].y;
        m = fminf(m, dy * dy + dx * dx);
    }
    m = fminf(m, __shfl_xor(m, 1, 64));
    m = fminf(m, __shfl_xor(m, 2, 64));
    float d = (nfg == 0) ? 1.0f : sqrtf(m);
    if (q == 0) dist_raw[b * HW_ + pix] = d;
    float mm = d;
    #pragma unroll
    for (int off = 1; off < 64; off <<= 1)
        mm = fmaxf(mm, __shfl_xor(mm, off, 64));
    if (lane == 0) wmax[t >> 6] = mm;
    __syncthreads();
    if (t == 0) {
        float M = wmax[0];
        #pragma unroll
        for (int i = 1; i < 16; ++i) M = fmaxf(M, wmax[i]);
        atomicMax(dmax + b, __float_as_uint(M));
    }
}

// ---------------------------------------------------------------------------
// MFMA GEMM: 128o x 64n tile, 4 waves (64o x 32n each), 3 acc groups.
// Fused: inline attn (fp32 dot during staging), dist/attn epilogue, BN stats.
// ---------------------------------------------------------------------------
__global__ __launch_bounds__(256, 2) void gemm_kernel(
    const float* __restrict__ f_s, const float* __restrict__ sfb,
    const float* __restrict__ w, const unsigned short* __restrict__ wprep,
    const float* __restrict__ dist_raw, const unsigned* __restrict__ dmax,
    float* __restrict__ y, float* __restrict__ gsum, float* __restrict__ gsumsq)
{
    __shared__ unsigned short Lf[2048], Ls[2048];   // [kg(4)][p(64)][j(8)] bf16
    __shared__ float attn_sm[4][64];
    __shared__ float attn_fin[64];
    __shared__ float red[2][64][2];

    int bx = blockIdx.x;
    int ot = bx & 1, nt = bx >> 1;
    int oBase = ot * 128;
    int nBase = nt * 64;
    int b = nBase >> 12, pBase = nBase & 4095;
    int t = threadIdx.x;
    int lane = t & 63, g = t >> 6;          // g = wave id = staging kg
    int wo = g >> 1, wn = g & 1;
    int l15 = lane & 15, kq = lane >> 4;

    const float* fB = f_s + (size_t)b * C_IN * HW_ + pBase;
    const float* sB = sfb + (size_t)b * C_IN * HW_ + pBase;

    f32x4 acc[3][4][2];
    #pragma unroll
    for (int m = 0; m < 3; ++m)
        #pragma unroll
        for (int fo = 0; fo < 4; ++fo)
            #pragma unroll
            for (int fn = 0; fn < 2; ++fn)
                acc[m][fo][fn] = (f32x4){0.f, 0.f, 0.f, 0.f};

    float ap = 0.f;
    const bf16x8* WP = (const bf16x8*)wprep;
    const bf16x8* BFr = (const bf16x8*)Lf;
    const bf16x8* BSr = (const bf16x8*)Ls;

    for (int ks = 0; ks < 8; ++ks) {
        // ---- stage 32k x 64p of f_s and sfb (transpose to k-contig bf16) ----
        {
            const float* fr = fB + (size_t)(ks * 32 + g * 8) * HW_ + lane;
            const float* sr = sB + (size_t)(ks * 32 + g * 8) * HW_ + lane;
            float fv[8], sv[8];
            #pragma unroll
            for (int j = 0; j < 8; ++j) {
                fv[j] = fr[(size_t)j * HW_];
                sv[j] = sr[(size_t)j * HW_];
                ap += fv[j] * sv[j];
            }
            #pragma unroll
            for (int q = 0; q < 2; ++q) {
                u16x4 pf, ps;
                #pragma unroll
                for (int jj = 0; jj < 4; ++jj) {
                    pf[jj] = f2bf(fv[q * 4 + jj]);
                    ps[jj] = f2bf(sv[q * 4 + jj]);
                }
                ((u16x4*)Lf)[(g * 64 + lane) * 2 + q] = pf;
                ((u16x4*)Ls)[(g * 64 + lane) * 2 + q] = ps;
            }
        }
        __syncthreads();
        // ---- MFMA phase ----
        bf16x8 bf0 = BFr[kq * 64 + wn * 32 + l15];
        bf16x8 bf1 = BFr[kq * 64 + wn * 32 + 16 + l15];
        bf16x8 bs0 = BSr[kq * 64 + wn * 32 + l15];
        bf16x8 bs1 = BSr[kq * 64 + wn * 32 + 16 + l15];
        #pragma unroll
        for (int fo = 0; fo < 4; ++fo) {
            int o = oBase + wo * 64 + fo * 16 + l15;
            bf16x8 a1 = WP[((0 * 8 + ks) * 4 + kq) * 256 + o];
            bf16x8 a2 = WP[((1 * 8 + ks) * 4 + kq) * 256 + o];
            bf16x8 a3 = WP[((2 * 8 + ks) * 4 + kq) * 256 + o];
            acc[0][fo][0] = __builtin_amdgcn_mfma_f32_16x16x32_bf16(a1, bf0, acc[0][fo][0], 0, 0, 0);
            acc[0][fo][1] = __builtin_amdgcn_mfma_f32_16x16x32_bf16(a1, bf1, acc[0][fo][1], 0, 0, 0);
            acc[1][fo][0] = __builtin_amdgcn_mfma_f32_16x16x32_bf16(a2, bs0, acc[1][fo][0], 0, 0, 0);
            acc[1][fo][1] = __builtin_amdgcn_mfma_f32_16x16x32_bf16(a2, bs1, acc[1][fo][1], 0, 0, 0);
            acc[2][fo][0] = __builtin_amdgcn_mfma_f32_16x16x32_bf16(a3, bf0, acc[2][fo][0], 0, 0, 0);
            acc[2][fo][1] = __builtin_amdgcn_mfma_f32_16x16x32_bf16(a3, bf1, acc[2][fo][1], 0, 0, 0);
        }
        __syncthreads();
    }

    // ---- attn finalize (fp32, pre-rounding values) ----
    attn_sm[g][lane] = ap;
    __syncthreads();
    if (t < 64) {
        float a = attn_sm[0][t] + attn_sm[1][t] + attn_sm[2][t] + attn_sm[3][t];
        attn_fin[t] = 1.f / (1.f + expf(-a));
    }
    __syncthreads();

    // ---- epilogue: combine, store y, BN partial stats ----
    float dinv = 1.0f / (__uint_as_float(dmax[b]) + 1e-6f);
    const float* dR = dist_raw + b * HW_ + pBase;
    float at[2], dn[2];
    #pragma unroll
    for (int fn = 0; fn < 2; ++fn) {
        int nb = wn * 32 + fn * 16 + l15;
        at[fn] = attn_fin[nb];
        dn[fn] = dR[nb] * dinv;
    }
    float s_acc[4][4], ss_acc[4][4];
    #pragma unroll
    for (int fo = 0; fo < 4; ++fo) {
        #pragma unroll
        for (int r = 0; r < 4; ++r) {
            int o = oBase + wo * 64 + fo * 16 + kq * 4 + r;
            float wd = w[(size_t)o * KW_ + 768];
            float s = 0.f, ss = 0.f;
            #pragma unroll
            for (int fn = 0; fn < 2; ++fn) {
                float v = acc[0][fo][fn][r] + acc[1][fo][fn][r]
                        + at[fn] * acc[2][fo][fn][r] + wd * dn[fn];
                int nb = wn * 32 + fn * 16 + l15;
                y[((size_t)b * C_IN + o) * HW_ + pBase + nb] = v;
                s += v; ss += v * v;
            }
            s_acc[fo][r] = s; ss_acc[fo][r] = ss;
        }
    }
    #pragma unroll
    for (int m = 8; m; m >>= 1) {
        #pragma unroll
        for (int fo = 0; fo < 4; ++fo)
            #pragma unroll
            for (int r = 0; r < 4; ++r) {
                s_acc[fo][r]  += __shfl_xor(s_acc[fo][r],  m, 64);
                ss_acc[fo][r] += __shfl_xor(ss_acc[fo][r], m, 64);
            }
    }
    if (wn == 1 && l15 == 0) {
        #pragma unroll
        for (int fo = 0; fo < 4; ++fo)
            #pragma unroll
            for (int r = 0; r < 4; ++r) {
                int ol = fo * 16 + kq * 4 + r;
                red[wo][ol][0] = s_acc[fo][r];
                red[wo][ol][1] = ss_acc[fo][r];
            }
    }
    __syncthreads();
    if (wn == 0 && l15 == 0) {
        #pragma unroll
        for (int fo = 0; fo < 4; ++fo)
            #pragma unroll
            for (int r = 0; r < 4; ++r) {
                int ol = fo * 16 + kq * 4 + r;
                int o = oBase + wo * 64 + ol;
                atomicAdd(&gsum[o],   s_acc[fo][r]  + red[wo][ol][0]);
                atomicAdd(&gsumsq[o], ss_acc[fo][r] + red[wo][ol][1]);
            }
    }
}

// ---------------------------------------------------------------------------
// BN finalize + relu, in-place on y
// ---------------------------------------------------------------------------
__global__ __launch_bounds__(256) void bn_kernel(
    const float* __restrict__ gsum, const float* __restrict__ gsumsq,
    const float* __restrict__ gamma, const float* __restrict__ beta,
    float* __restrict__ y)
{
    int bo = blockIdx.x;
    int o = bo & 255;
    float mean = gsum[o] * (1.0f / NPIX_BN);
    float var  = gsumsq[o] * (1.0f / NPIX_BN) - mean * mean;
    float sc = gamma[o] * rsqrtf(var + 1e-5f);
    float sh = beta[o] - mean * sc;
    float4* p = (float4*)(y + (size_t)bo * HW_);
    int t = threadIdx.x;
    #pragma unroll
    for (int r = 0; r < 4; ++r) {
        float4 v = p[r * 256 + t];
        v.x = fmaxf(v.x * sc + sh, 0.f);
        v.y = fmaxf(v.y * sc + sh, 0.f);
        v.z = fmaxf(v.z * sc + sh, 0.f);
        v.w = fmaxf(v.w * sc + sh, 0.f);
        p[r * 256 + t] = v;
    }
}

// ---------------------------------------------------------------------------
// ws layout (float units):
//   [0,     32768)  dist_raw
//   [32768, 32776)  dmax (uint)
//   [32784, 33040)  gsum
//   [33040, 33296)  gsumsq
//   [33296, ... )   wprep: 196608 ushort = 393216 B
// ---------------------------------------------------------------------------
extern "C" void kernel_launch(void* const* d_in, const int* in_sizes, int n_in,
                              void* d_out, int out_size, void* d_ws, size_t ws_size,
                              hipStream_t stream)
{
    const float* f_s   = (const float*)d_in[0];
    const float* sfb   = (const float*)d_in[1];
    const float* mask  = (const float*)d_in[2];
    const float* w     = (const float*)d_in[3];
    const float* gamma = (const float*)d_in[4];
    const float* beta  = (const float*)d_in[5];
    float* out = (float*)d_out;
    float* ws  = (float*)d_ws;

    float*          dist_raw = ws;
    unsigned*       dmax     = (unsigned*)(ws + 32768);
    float*          gsum     = ws + 32784;
    float*          gsumsq   = ws + 33040;
    unsigned short* wprep    = (unsigned short*)(ws + 33296);

    hipMemsetAsync(ws + 32768, 0, (33296 - 32768) * 4, stream);

    prep_w<<<768, 256, 0, stream>>>(w, wprep);
    dist_kernel<<<dim3(8, 16), 1024, 0, stream>>>(mask, dist_raw, dmax);
    gemm_kernel<<<1024, 256, 0, stream>>>(f_s, sfb, w, wprep, dist_raw, dmax,
                                          out, gsum, gsumsq);
    bn_kernel<<<2048, 256, 0, stream>>>(gsum, gsumsq, gamma, beta, out);
}

// Round 3
// 245.550 us; speedup vs baseline: 1.4429x; 1.0060x over previous
//
#include <hip/hip_runtime.h>
#include <math.h>

#define C_IN   256
#define HW_    4096
#define KW_    769
#define NPIX_BN 32768.0f

typedef short bf16x8 __attribute__((ext_vector_type(8)));
typedef float f32x4  __attribute__((ext_vector_type(4)));
typedef unsigned short u16x4 __attribute__((ext_vector_type(4)));

__device__ inline unsigned short f2bf(float x){
    unsigned u = __float_as_uint(x);
    u += 0x7fffu + ((u >> 16) & 1u);      // RNE
    return (unsigned short)(u >> 16);
}

// ---------------------------------------------------------------------------
// prep_w: w fp32 [256][769] -> wprep bf16 fragment-ordered
// layout: chunk = ((m*8+ks)*4+kq)*256 + o, 8 k-contiguous bf16 per chunk
// ---------------------------------------------------------------------------
__global__ __launch_bounds__(256) void prep_w(
    const float* __restrict__ w, unsigned short* __restrict__ wp)
{
    int idx = blockIdx.x * 256 + threadIdx.x;     // 196608 total
    int j  = idx & 7;
    int o  = (idx >> 3) & 255;
    int t2 = idx >> 11;                           // m*32 + ks*4 + kq
    int kq = t2 & 3, ks = (t2 >> 2) & 7, m = t2 >> 5;
    int c  = m * 256 + ks * 32 + kq * 8 + j;
    wp[idx] = f2bf(w[(size_t)o * KW_ + c]);
}

// ---------------------------------------------------------------------------
// dist kernel: ballot-compacted fg list + brute-force min distance
// ---------------------------------------------------------------------------
__global__ __launch_bounds__(1024) void dist_kernel(
    const float* __restrict__ mask, float* __restrict__ dist_raw,
    unsigned* __restrict__ dmax)
{
    __shared__ float2 fg[4096];
    __shared__ int cnt;
    __shared__ float wmax[16];
    int b = blockIdx.x, tile = blockIdx.y;
    int t = threadIdx.x, lane = t & 63;
    if (t == 0) cnt = 0;
    __syncthreads();
    const float* mb = mask + (size_t)b * 65536;
    #pragma unroll
    for (int r = 0; r < 4; ++r) {
        int pp = r * 1024 + t;
        int i = pp >> 6, j = pp & 63;
        bool pred = mb[i * 1024 + j * 4] > 0.5f;
        unsigned long long bal = __ballot(pred);
        int base = 0;
        if (lane == 0) base = atomicAdd(&cnt, __popcll(bal));
        base = __shfl(base, 0, 64);
        if (pred)
            fg[base + __popcll(bal & ((1ull << lane) - 1ull))] =
                make_float2((float)i, (float)j);
    }
    __syncthreads();
    int nfg = cnt;
    int pix = tile * 256 + (t >> 2);
    int q = t & 3;
    float py = (float)(pix >> 6), px = (float)(pix & 63);
    float m = 3.4e38f;
    for (int it = q; it < nfg; it += 4) {
        float dy = py - fg[it].x;
        float dx = px - fg[it].y;
        m = fminf(m, dy * dy + dx * dx);
    }
    m = fminf(m, __shfl_xor(m, 1, 64));
    m = fminf(m, __shfl_xor(m, 2, 64));
    float d = (nfg == 0) ? 1.0f : sqrtf(m);
    if (q == 0) dist_raw[b * HW_ + pix] = d;
    float mm = d;
    #pragma unroll
    for (int off = 1; off < 64; off <<= 1)
        mm = fmaxf(mm, __shfl_xor(mm, off, 64));
    if (lane == 0) wmax[t >> 6] = mm;
    __syncthreads();
    if (t == 0) {
        float M = wmax[0];
        #pragma unroll
        for (int i = 1; i < 16; ++i) M = fmaxf(M, wmax[i]);
        atomicMax(dmax + b, __float_as_uint(M));
    }
}

// ---------------------------------------------------------------------------
// MFMA GEMM, pipelined: double-buffered LDS, ONE barrier per K-step,
// register prefetch issued after the barrier (stays in flight across MFMAs).
// 128o x 64n tile, 4 waves (64o x 32n each), 3 acc groups.
// ---------------------------------------------------------------------------
__global__ __launch_bounds__(256, 2) void gemm_kernel(
    const float* __restrict__ f_s, const float* __restrict__ sfb,
    const float* __restrict__ w, const unsigned short* __restrict__ wprep,
    const float* __restrict__ dist_raw, const unsigned* __restrict__ dmax,
    float* __restrict__ y, float* __restrict__ gsum, float* __restrict__ gsumsq)
{
    __shared__ unsigned short Lf[2][2048], Ls[2][2048];  // [buf][kq(4)][p(64)][j(8)]
    __shared__ float attn_sm[4][64];
    __shared__ float attn_fin[64];
    __shared__ float red[2][64][2];

    int bx = blockIdx.x;
    int ot = bx & 1, nt = bx >> 1;
    int oBase = ot * 128;
    int nBase = nt * 64;
    int b = nBase >> 12, pBase = nBase & 4095;
    int t = threadIdx.x;
    int lane = t & 63, g = t >> 6;          // g = wave id = staging kq slot
    int wo = g >> 1, wn = g & 1;
    int l15 = lane & 15, kq = lane >> 4;

    const float* fB = f_s + (size_t)b * C_IN * HW_ + pBase + lane;
    const float* sB = sfb + (size_t)b * C_IN * HW_ + pBase + lane;

    f32x4 acc[3][4][2];
    #pragma unroll
    for (int m = 0; m < 3; ++m)
        #pragma unroll
        for (int fo = 0; fo < 4; ++fo)
            #pragma unroll
            for (int fn = 0; fn < 2; ++fn)
                acc[m][fo][fn] = (f32x4){0.f, 0.f, 0.f, 0.f};

    float ap = 0.f;
    const bf16x8* WP = (const bf16x8*)wprep;

    // prologue: load ks=0 staging values into registers
    float fv[8], sv[8];
    #pragma unroll
    for (int j = 0; j < 8; ++j) {
        fv[j] = fB[(size_t)(g * 8 + j) * HW_];
        sv[j] = sB[(size_t)(g * 8 + j) * HW_];
    }

    #pragma unroll
    for (int ks = 0; ks < 8; ++ks) {
        int cur = ks & 1;
        // ---- convert + attn-dot + LDS write (zero-conflict b64 writes) ----
        #pragma unroll
        for (int j = 0; j < 8; ++j) ap += fv[j] * sv[j];
        #pragma unroll
        for (int q = 0; q < 2; ++q) {
            u16x4 pf, ps;
            #pragma unroll
            for (int jj = 0; jj < 4; ++jj) {
                pf[jj] = f2bf(fv[q * 4 + jj]);
                ps[jj] = f2bf(sv[q * 4 + jj]);
            }
            ((u16x4*)Lf[cur])[(g * 64 + lane) * 2 + q] = pf;
            ((u16x4*)Ls[cur])[(g * 64 + lane) * 2 + q] = ps;
        }
        __syncthreads();
        // ---- prefetch next K-step AFTER the barrier (survives the drain) ----
        if (ks < 7) {
            #pragma unroll
            for (int j = 0; j < 8; ++j) {
                fv[j] = fB[(size_t)((ks + 1) * 32 + g * 8 + j) * HW_];
                sv[j] = sB[(size_t)((ks + 1) * 32 + g * 8 + j) * HW_];
            }
        }
        // ---- MFMA phase ----
        const bf16x8* BFr = (const bf16x8*)Lf[cur];
        const bf16x8* BSr = (const bf16x8*)Ls[cur];
        bf16x8 bf0 = BFr[kq * 64 + wn * 32 + l15];
        bf16x8 bf1 = BFr[kq * 64 + wn * 32 + 16 + l15];
        bf16x8 bs0 = BSr[kq * 64 + wn * 32 + l15];
        bf16x8 bs1 = BSr[kq * 64 + wn * 32 + 16 + l15];
        #pragma unroll
        for (int fo = 0; fo < 4; ++fo) {
            int o = oBase + wo * 64 + fo * 16 + l15;
            bf16x8 a1 = WP[((0 * 8 + ks) * 4 + kq) * 256 + o];
            bf16x8 a2 = WP[((1 * 8 + ks) * 4 + kq) * 256 + o];
            bf16x8 a3 = WP[((2 * 8 + ks) * 4 + kq) * 256 + o];
            acc[0][fo][0] = __builtin_amdgcn_mfma_f32_16x16x32_bf16(a1, bf0, acc[0][fo][0], 0, 0, 0);
            acc[0][fo][1] = __builtin_amdgcn_mfma_f32_16x16x32_bf16(a1, bf1, acc[0][fo][1], 0, 0, 0);
            acc[1][fo][0] = __builtin_amdgcn_mfma_f32_16x16x32_bf16(a2, bs0, acc[1][fo][0], 0, 0, 0);
            acc[1][fo][1] = __builtin_amdgcn_mfma_f32_16x16x32_bf16(a2, bs1, acc[1][fo][1], 0, 0, 0);
            acc[2][fo][0] = __builtin_amdgcn_mfma_f32_16x16x32_bf16(a3, bf0, acc[2][fo][0], 0, 0, 0);
            acc[2][fo][1] = __builtin_amdgcn_mfma_f32_16x16x32_bf16(a3, bf1, acc[2][fo][1], 0, 0, 0);
        }
        // no trailing barrier: next iteration writes the OTHER LDS buffer;
        // per-wave LDS ops are in-order, cross-wave hazards covered by the
        // single barrier above (write of buf X at step ks+2 happens after
        // barrier ks+1, by which time all MFMA reads of step ks are done).
    }

    __syncthreads();
    // ---- attn finalize (fp32, pre-rounding values) ----
    attn_sm[g][lane] = ap;
    __syncthreads();
    if (t < 64) {
        float a = attn_sm[0][t] + attn_sm[1][t] + attn_sm[2][t] + attn_sm[3][t];
        attn_fin[t] = 1.f / (1.f + __expf(-a));
    }
    __syncthreads();

    // ---- epilogue: combine, store y, BN partial stats ----
    float dinv = 1.0f / (__uint_as_float(dmax[b]) + 1e-6f);
    const float* dR = dist_raw + b * HW_ + pBase;
    float at[2], dn[2];
    #pragma unroll
    for (int fn = 0; fn < 2; ++fn) {
        int nb = wn * 32 + fn * 16 + l15;
        at[fn] = attn_fin[nb];
        dn[fn] = dR[nb] * dinv;
    }
    float s_acc[4][4], ss_acc[4][4];
    #pragma unroll
    for (int fo = 0; fo < 4; ++fo) {
        #pragma unroll
        for (int r = 0; r < 4; ++r) {
            int o = oBase + wo * 64 + fo * 16 + kq * 4 + r;
            float wd = w[(size_t)o * KW_ + 768];
            float s = 0.f, ss = 0.f;
            #pragma unroll
            for (int fn = 0; fn < 2; ++fn) {
                float v = acc[0][fo][fn][r] + acc[1][fo][fn][r]
                        + at[fn] * acc[2][fo][fn][r] + wd * dn[fn];
                int nb = wn * 32 + fn * 16 + l15;
                y[((size_t)b * C_IN + o) * HW_ + pBase + nb] = v;
                s += v; ss += v * v;
            }
            s_acc[fo][r] = s; ss_acc[fo][r] = ss;
        }
    }
    #pragma unroll
    for (int m = 8; m; m >>= 1) {
        #pragma unroll
        for (int fo = 0; fo < 4; ++fo)
            #pragma unroll
            for (int r = 0; r < 4; ++r) {
                s_acc[fo][r]  += __shfl_xor(s_acc[fo][r],  m, 64);
                ss_acc[fo][r] += __shfl_xor(ss_acc[fo][r], m, 64);
            }
    }
    if (wn == 1 && l15 == 0) {
        #pragma unroll
        for (int fo = 0; fo < 4; ++fo)
            #pragma unroll
            for (int r = 0; r < 4; ++r) {
                int ol = fo * 16 + kq * 4 + r;
                red[wo][ol][0] = s_acc[fo][r];
                red[wo][ol][1] = ss_acc[fo][r];
            }
    }
    __syncthreads();
    if (wn == 0 && l15 == 0) {
        #pragma unroll
        for (int fo = 0; fo < 4; ++fo)
            #pragma unroll
            for (int r = 0; r < 4; ++r) {
                int ol = fo * 16 + kq * 4 + r;
                int o = oBase + wo * 64 + ol;
                atomicAdd(&gsum[o],   s_acc[fo][r]  + red[wo][ol][0]);
                atomicAdd(&gsumsq[o], ss_acc[fo][r] + red[wo][ol][1]);
            }
    }
}

// ---------------------------------------------------------------------------
// BN finalize + relu, in-place on y
// ---------------------------------------------------------------------------
__global__ __launch_bounds__(256) void bn_kernel(
    const float* __restrict__ gsum, const float* __restrict__ gsumsq,
    const float* __restrict__ gamma, const float* __restrict__ beta,
    float* __restrict__ y)
{
    int bo = blockIdx.x;
    int o = bo & 255;
    float mean = gsum[o] * (1.0f / NPIX_BN);
    float var  = gsumsq[o] * (1.0f / NPIX_BN) - mean * mean;
    float sc = gamma[o] * rsqrtf(var + 1e-5f);
    float sh = beta[o] - mean * sc;
    float4* p = (float4*)(y + (size_t)bo * HW_);
    int t = threadIdx.x;
    #pragma unroll
    for (int r = 0; r < 4; ++r) {
        float4 v = p[r * 256 + t];
        v.x = fmaxf(v.x * sc + sh, 0.f);
        v.y = fmaxf(v.y * sc + sh, 0.f);
        v.z = fmaxf(v.z * sc + sh, 0.f);
        v.w = fmaxf(v.w * sc + sh, 0.f);
        p[r * 256 + t] = v;
    }
}

// ---------------------------------------------------------------------------
// ws layout (float units):
//   [0,     32768)  dist_raw
//   [32768, 32776)  dmax (uint)
//   [32784, 33040)  gsum
//   [33040, 33296)  gsumsq
//   [33296, ... )   wprep: 196608 ushort = 393216 B
// ---------------------------------------------------------------------------
extern "C" void kernel_launch(void* const* d_in, const int* in_sizes, int n_in,
                              void* d_out, int out_size, void* d_ws, size_t ws_size,
                              hipStream_t stream)
{
    const float* f_s   = (const float*)d_in[0];
    const float* sfb   = (const float*)d_in[1];
    const float* mask  = (const float*)d_in[2];
    const float* w     = (const float*)d_in[3];
    const float* gamma = (const float*)d_in[4];
    const float* beta  = (const float*)d_in[5];
    float* out = (float*)d_out;
    float* ws  = (float*)d_ws;

    float*          dist_raw = ws;
    unsigned*       dmax     = (unsigned*)(ws + 32768);
    float*          gsum     = ws + 32784;
    float*          gsumsq   = ws + 33040;
    unsigned short* wprep    = (unsigned short*)(ws + 33296);

    hipMemsetAsync(ws + 32768, 0, (33296 - 32768) * 4, stream);

    prep_w<<<768, 256, 0, stream>>>(w, wprep);
    dist_kernel<<<dim3(8, 16), 1024, 0, stream>>>(mask, dist_raw, dmax);
    gemm_kernel<<<1024, 256, 0, stream>>>(f_s, sfb, w, wprep, dist_raw, dmax,
                                          out, gsum, gsumsq);
    bn_kernel<<<2048, 256, 0, stream>>>(gsum, gsumsq, gamma, beta, out);
}